// Round 1
// baseline (280.497 us; speedup 1.0000x reference)
//
#include <hip/hip_runtime.h>
#include <math.h>

// Batched expm of 4x4 fp32 matrices: out[m] = expm(A[m] * t[m / S]).
// One thread per matrix; all 4x4 state in registers (fully unrolled).
// Scaling-and-squaring identical in structure to the reference:
//   s = clip(ceil(log2(max(||Qt||_inf,1e-30)/0.5)), 0, 16)
//   As = Qt * 2^-s ; P = Taylor(As) ; P = P^(2^s)
// Taylor evaluated to degree 9 via Paterson-Stockmeyer (4 matmuls instead of 9
// sequential ones; truncation 0.5^10/10! ~ 2.7e-10 rel, below fp32 noise):
//   P = ((C9*A3+C8*A2+C7*A+C6*I)*A3 + (C5*A2+C4*A+C3*I))*A3 + (C2*A2+A+I)

typedef float f4 __attribute__((ext_vector_type(4)));

__device__ __forceinline__ void mm4(float* __restrict__ D,
                                    const float* __restrict__ X,
                                    const float* __restrict__ Y)
{
    #pragma unroll
    for (int i = 0; i < 4; ++i) {
        const float x0 = X[4*i+0], x1 = X[4*i+1];
        const float x2 = X[4*i+2], x3 = X[4*i+3];
        #pragma unroll
        for (int j = 0; j < 4; ++j) {
            float v = x0 * Y[j];
            v = __builtin_fmaf(x1, Y[4+j],  v);
            v = __builtin_fmaf(x2, Y[8+j],  v);
            v = __builtin_fmaf(x3, Y[12+j], v);
            D[4*i+j] = v;
        }
    }
}

__global__ void __launch_bounds__(256) expm4_kernel(
    const float* __restrict__ A,
    const float* __restrict__ tvec,
    float* __restrict__ out,
    int M, int S)
{
    const int m = blockIdx.x * 256 + threadIdx.x;
    if (m >= M) return;

    const float t = tvec[m / S];   // wave-uniform (S is a multiple of 64)

    // ---- load A[m] (64 B contiguous) and form Qt = A*t ----
    float a[16];
    const f4* Ap = reinterpret_cast<const f4*>(A) + (size_t)m * 4;
    #pragma unroll
    for (int i = 0; i < 4; ++i) {
        f4 v = Ap[i];
        a[4*i+0] = v.x * t;
        a[4*i+1] = v.y * t;
        a[4*i+2] = v.z * t;
        a[4*i+3] = v.w * t;
    }

    // ---- infinity norm (max abs row sum) ----
    float nrm = 0.0f;
    #pragma unroll
    for (int i = 0; i < 4; ++i) {
        float rs = fabsf(a[4*i+0]) + fabsf(a[4*i+1])
                 + fabsf(a[4*i+2]) + fabsf(a[4*i+3]);
        nrm = fmaxf(nrm, rs);
    }

    // ---- squaring count + scale (matches jnp expression) ----
    float sf = ceilf(log2f(fmaxf(nrm, 1e-30f) * 2.0f));  // log2(nrm/0.5)
    sf = fminf(fmaxf(sf, 0.0f), 16.0f);
    const int   si    = (int)sf;
    const float scale = exp2f(-sf);
    #pragma unroll
    for (int i = 0; i < 16; ++i) a[i] *= scale;          // a = As

    // ---- powers ----
    float A2[16], A3[16];
    mm4(A2, a, a);     // As^2
    mm4(A3, A2, a);    // As^3

    // ---- Paterson-Stockmeyer groups (computed early so a, A2 die) ----
    constexpr float C2 = 1.0f/2.0f,    C3 = 1.0f/6.0f;
    constexpr float C4 = 1.0f/24.0f,   C5 = 1.0f/120.0f;
    constexpr float C6 = 1.0f/720.0f,  C7 = 1.0f/5040.0f;
    constexpr float C8 = 1.0f/40320.0f, C9 = 1.0f/362880.0f;

    float G[16], HI[16], PI[16];
    #pragma unroll
    for (int i = 0; i < 16; ++i) {
        G[i]  = __builtin_fmaf(C9, A3[i],
                __builtin_fmaf(C8, A2[i], C7 * a[i]));
        HI[i] = __builtin_fmaf(C5, A2[i], C4 * a[i]);
        PI[i] = __builtin_fmaf(C2, A2[i], a[i]);
    }
    G[0]  += C6; G[5]  += C6; G[10] += C6; G[15] += C6;
    HI[0] += C3; HI[5] += C3; HI[10] += C3; HI[15] += C3;
    PI[0] += 1.0f; PI[5] += 1.0f; PI[10] += 1.0f; PI[15] += 1.0f;
    // a, A2 now dead.

    // ---- H = G*A3 + HI ----
    float H[16];
    #pragma unroll
    for (int i = 0; i < 4; ++i) {
        const float g0 = G[4*i+0], g1 = G[4*i+1];
        const float g2 = G[4*i+2], g3 = G[4*i+3];
        #pragma unroll
        for (int j = 0; j < 4; ++j) {
            float v = HI[4*i+j];
            v = __builtin_fmaf(g0, A3[j],    v);
            v = __builtin_fmaf(g1, A3[4+j],  v);
            v = __builtin_fmaf(g2, A3[8+j],  v);
            v = __builtin_fmaf(g3, A3[12+j], v);
            H[4*i+j] = v;
        }
    }

    // ---- P = H*A3 + PI ----
    float P[16];
    #pragma unroll
    for (int i = 0; i < 4; ++i) {
        const float h0 = H[4*i+0], h1 = H[4*i+1];
        const float h2 = H[4*i+2], h3 = H[4*i+3];
        #pragma unroll
        for (int j = 0; j < 4; ++j) {
            float v = PI[4*i+j];
            v = __builtin_fmaf(h0, A3[j],    v);
            v = __builtin_fmaf(h1, A3[4+j],  v);
            v = __builtin_fmaf(h2, A3[8+j],  v);
            v = __builtin_fmaf(h3, A3[12+j], v);
            P[4*i+j] = v;
        }
    }

    // ---- undo scaling: square si times (2x-unrolled ping-pong, no copies
    //      in the even case; wave pays max si over its lanes) ----
    int it = si;
    while (it >= 2) {
        float Q[16];
        mm4(Q, P, P);
        mm4(P, Q, Q);
        it -= 2;
    }
    if (it) {
        float Q[16];
        mm4(Q, P, P);
        #pragma unroll
        for (int i = 0; i < 16; ++i) P[i] = Q[i];
    }

    // ---- store (64 B contiguous, nontemporal: keep the input L3-resident) ----
    f4* Op = reinterpret_cast<f4*>(out) + (size_t)m * 4;
    #pragma unroll
    for (int i = 0; i < 4; ++i) {
        f4 v;
        v.x = P[4*i+0]; v.y = P[4*i+1]; v.z = P[4*i+2]; v.w = P[4*i+3];
        __builtin_nontemporal_store(v, Op + i);
    }
}

extern "C" void kernel_launch(void* const* d_in, const int* in_sizes, int n_in,
                              void* d_out, int out_size, void* d_ws, size_t ws_size,
                              hipStream_t stream) {
    const float* A    = (const float*)d_in[0];   // [B, S, 4, 4] fp32
    const float* tvec = (const float*)d_in[1];   // [B] fp32
    float* out        = (float*)d_out;           // [B, S, 4, 4] fp32

    const int B = in_sizes[1];
    const int M = in_sizes[0] / 16;              // total 4x4 matrices
    const int S = M / B;                         // matrices per batch item

    const int threads = 256;
    const int blocks  = (M + threads - 1) / threads;
    expm4_kernel<<<blocks, threads, 0, stream>>>(A, tvec, out, M, S);
}

// Round 2
// 233.225 us; speedup vs baseline: 1.2027x; 1.2027x over previous
//
#include <hip/hip_runtime.h>
#include <math.h>

// Batched expm of 4x4 fp32 matrices: out[m] = expm(A[m] * t[m / S]).
// One thread per matrix; all 4x4 state in registers (fully unrolled).
// Scaling-and-squaring identical in structure to the reference:
//   s = clip(ceil(log2(max(||Qt||_inf,1e-30)/0.5)), 0, 16)
//   As = Qt * 2^-s ; P = Taylor(As) ; P = P^(2^s)
// Taylor evaluated to degree 9 via Paterson-Stockmeyer (4 matmuls instead of 9
// sequential ones; truncation 0.5^10/10! ~ 2.7e-10 rel, below fp32 noise).
//
// Global<->register movement is staged through LDS so every global memory
// instruction is a contiguous 1 KB/wave (coalesced float4) access. Without
// staging, each thread's 4x16B strided accesses touch 64 distinct lines per
// instruction -> L1 request-rate wall at ~2.4 TB/s (measured rounds 0/1).
// LDS slot stride = 20 floats (80 B): 16B-aligned for b128 ops, bank period 8.

typedef float f4 __attribute__((ext_vector_type(4)));

constexpr int LDS_STRIDE = 20;   // floats per matrix slot

__device__ __forceinline__ void mm4(float* __restrict__ D,
                                    const float* __restrict__ X,
                                    const float* __restrict__ Y)
{
    #pragma unroll
    for (int i = 0; i < 4; ++i) {
        const float x0 = X[4*i+0], x1 = X[4*i+1];
        const float x2 = X[4*i+2], x3 = X[4*i+3];
        #pragma unroll
        for (int j = 0; j < 4; ++j) {
            float v = x0 * Y[j];
            v = __builtin_fmaf(x1, Y[4+j],  v);
            v = __builtin_fmaf(x2, Y[8+j],  v);
            v = __builtin_fmaf(x3, Y[12+j], v);
            D[4*i+j] = v;
        }
    }
}

__global__ void __launch_bounds__(256) expm4_kernel(
    const float* __restrict__ A,
    const float* __restrict__ tvec,
    float* __restrict__ out,
    int M, int S)
{
    __shared__ float lds[256 * LDS_STRIDE];   // 20 KB

    const int tid = threadIdx.x;
    const long long mat0 = (long long)blockIdx.x * 256;   // first matrix of block
    const long long gtot = (long long)M * 4;              // total float4 groups

    // ---- coalesced load: 4 sweeps of 1 KB/wave into LDS ----
    const f4* Ag = reinterpret_cast<const f4*>(A);
    const long long g0 = mat0 * 4;
    #pragma unroll
    for (int it = 0; it < 4; ++it) {
        const int g = it * 256 + tid;         // group within block
        const long long gg = g0 + g;
        if (gg < gtot) {
            f4 v = Ag[gg];
            *reinterpret_cast<f4*>(&lds[(g >> 2) * LDS_STRIDE + (g & 3) * 4]) = v;
        }
    }
    __syncthreads();

    // ---- per-thread matrix from own LDS slot; form Qt = A*t ----
    const long long m = mat0 + tid;
    const float t = tvec[(int)(m / S)];       // block-uniform (256 divides S)

    float a[16];
    #pragma unroll
    for (int k = 0; k < 4; ++k) {
        f4 v = *reinterpret_cast<const f4*>(&lds[tid * LDS_STRIDE + k * 4]);
        a[4*k+0] = v.x * t;
        a[4*k+1] = v.y * t;
        a[4*k+2] = v.z * t;
        a[4*k+3] = v.w * t;
    }

    // ---- infinity norm (max abs row sum) ----
    float nrm = 0.0f;
    #pragma unroll
    for (int i = 0; i < 4; ++i) {
        float rs = fabsf(a[4*i+0]) + fabsf(a[4*i+1])
                 + fabsf(a[4*i+2]) + fabsf(a[4*i+3]);
        nrm = fmaxf(nrm, rs);
    }

    // ---- squaring count + scale (matches jnp expression) ----
    float sf = ceilf(log2f(fmaxf(nrm, 1e-30f) * 2.0f));  // log2(nrm/0.5)
    sf = fminf(fmaxf(sf, 0.0f), 16.0f);
    const int   si    = (int)sf;
    const float scale = exp2f(-sf);
    #pragma unroll
    for (int i = 0; i < 16; ++i) a[i] *= scale;          // a = As

    // ---- powers ----
    float A2[16], A3[16];
    mm4(A2, a, a);     // As^2
    mm4(A3, A2, a);    // As^3

    // ---- Paterson-Stockmeyer groups (computed early so a, A2 die) ----
    constexpr float C2 = 1.0f/2.0f,    C3 = 1.0f/6.0f;
    constexpr float C4 = 1.0f/24.0f,   C5 = 1.0f/120.0f;
    constexpr float C6 = 1.0f/720.0f,  C7 = 1.0f/5040.0f;
    constexpr float C8 = 1.0f/40320.0f, C9 = 1.0f/362880.0f;

    float G[16], HI[16], PI[16];
    #pragma unroll
    for (int i = 0; i < 16; ++i) {
        G[i]  = __builtin_fmaf(C9, A3[i],
                __builtin_fmaf(C8, A2[i], C7 * a[i]));
        HI[i] = __builtin_fmaf(C5, A2[i], C4 * a[i]);
        PI[i] = __builtin_fmaf(C2, A2[i], a[i]);
    }
    G[0]  += C6; G[5]  += C6; G[10] += C6; G[15] += C6;
    HI[0] += C3; HI[5] += C3; HI[10] += C3; HI[15] += C3;
    PI[0] += 1.0f; PI[5] += 1.0f; PI[10] += 1.0f; PI[15] += 1.0f;
    // a, A2 now dead.

    // ---- H = G*A3 + HI ----
    float H[16];
    #pragma unroll
    for (int i = 0; i < 4; ++i) {
        const float g0_ = G[4*i+0], g1_ = G[4*i+1];
        const float g2_ = G[4*i+2], g3_ = G[4*i+3];
        #pragma unroll
        for (int j = 0; j < 4; ++j) {
            float v = HI[4*i+j];
            v = __builtin_fmaf(g0_, A3[j],    v);
            v = __builtin_fmaf(g1_, A3[4+j],  v);
            v = __builtin_fmaf(g2_, A3[8+j],  v);
            v = __builtin_fmaf(g3_, A3[12+j], v);
            H[4*i+j] = v;
        }
    }

    // ---- P = H*A3 + PI ----
    float P[16];
    #pragma unroll
    for (int i = 0; i < 4; ++i) {
        const float h0 = H[4*i+0], h1 = H[4*i+1];
        const float h2 = H[4*i+2], h3 = H[4*i+3];
        #pragma unroll
        for (int j = 0; j < 4; ++j) {
            float v = PI[4*i+j];
            v = __builtin_fmaf(h0, A3[j],    v);
            v = __builtin_fmaf(h1, A3[4+j],  v);
            v = __builtin_fmaf(h2, A3[8+j],  v);
            v = __builtin_fmaf(h3, A3[12+j], v);
            P[4*i+j] = v;
        }
    }

    // ---- undo scaling: square si times (2x-unrolled ping-pong; wave pays
    //      max si over its lanes) ----
    int it2 = si;
    while (it2 >= 2) {
        float Q[16];
        mm4(Q, P, P);
        mm4(P, Q, Q);
        it2 -= 2;
    }
    if (it2) {
        float Q[16];
        mm4(Q, P, P);
        #pragma unroll
        for (int i = 0; i < 16; ++i) P[i] = Q[i];
    }

    // ---- write P to own LDS slot (same addresses this thread read; no
    //      cross-thread hazard, so no barrier needed before these writes) ----
    #pragma unroll
    for (int k = 0; k < 4; ++k) {
        f4 v;
        v.x = P[4*k+0]; v.y = P[4*k+1]; v.z = P[4*k+2]; v.w = P[4*k+3];
        *reinterpret_cast<f4*>(&lds[tid * LDS_STRIDE + k * 4]) = v;
    }
    __syncthreads();

    // ---- coalesced store: 4 sweeps of 1 KB/wave from LDS ----
    f4* Og = reinterpret_cast<f4*>(out);
    #pragma unroll
    for (int it = 0; it < 4; ++it) {
        const int g = it * 256 + tid;
        const long long gg = g0 + g;
        if (gg < gtot) {
            f4 v = *reinterpret_cast<const f4*>(&lds[(g >> 2) * LDS_STRIDE + (g & 3) * 4]);
            Og[gg] = v;
        }
    }
}

extern "C" void kernel_launch(void* const* d_in, const int* in_sizes, int n_in,
                              void* d_out, int out_size, void* d_ws, size_t ws_size,
                              hipStream_t stream) {
    const float* A    = (const float*)d_in[0];   // [B, S, 4, 4] fp32
    const float* tvec = (const float*)d_in[1];   // [B] fp32
    float* out        = (float*)d_out;           // [B, S, 4, 4] fp32

    const int B = in_sizes[1];
    const int M = in_sizes[0] / 16;              // total 4x4 matrices
    const int S = M / B;                         // matrices per batch item

    const int threads = 256;
    const int blocks  = (M + threads - 1) / threads;
    expm4_kernel<<<blocks, threads, 0, stream>>>(A, tvec, out, M, S);
}